// Round 3
// baseline (2441.935 us; speedup 1.0000x reference)
//
#include <hip/hip_runtime.h>
#include <stdint.h>

#define NT 500000
#define NC 100000
#define NM 20000
#define NE 500000

// Weq = W1 @ Wf (64x2) per relation; beq = b1 @ Wf (2) per relation.
__global__ __launch_bounds__(256) void weq_kernel(const float* __restrict__ W1c,
                                                  const float* __restrict__ b1c,
                                                  const float* __restrict__ W1m,
                                                  const float* __restrict__ b1m,
                                                  const float* __restrict__ Wf,
                                                  float* __restrict__ WeqC,
                                                  float* __restrict__ WeqM,
                                                  float* __restrict__ beq) {
    int t = threadIdx.x;
    if (t < 128) {
        int k = t >> 1, o = t & 1;
        float s = 0.0f;
        for (int j = 0; j < 64; j++) s += W1c[k * 64 + j] * Wf[j * 2 + o];
        WeqC[k * 2 + o] = s;
    } else {
        int k = (t - 128) >> 1, o = t & 1;
        float s = 0.0f;
        for (int j = 0; j < 64; j++) s += W1m[k * 64 + j] * Wf[j * 2 + o];
        WeqM[k * 2 + o] = s;
    }
    if (t < 4) {
        const float* b = (t < 2) ? b1c : b1m;
        int o = t & 1;
        float s = 0.0f;
        for (int j = 0; j < 64; j++) s += b[j] * Wf[j * 2 + o];
        beq[t] = s;
    }
}

// layer-0 aggregate-first: sum[dst][0:128] += feat[src][0:128]; cnt[dst] += 1
// 32 lanes per edge, float4 per lane (512 B per row, fully coalesced).
__global__ __launch_bounds__(256) void agg_feat(const float* __restrict__ feat,
                                                const int* __restrict__ src,
                                                const int* __restrict__ dst,
                                                float* __restrict__ sum,
                                                float* __restrict__ cnt) {
    int tid = blockIdx.x * 256 + threadIdx.x;
    int e = tid >> 5;
    if (e >= NE) return;
    int c4 = (tid & 31) * 4;
    int s = src[e], d = dst[e];
    const float4 v = *(const float4*)(feat + (size_t)s * 128 + c4);
    float* sp = sum + (size_t)d * 128 + c4;
    atomicAdd(sp + 0, v.x);
    atomicAdd(sp + 1, v.y);
    atomicAdd(sp + 2, v.z);
    atomicAdd(sp + 3, v.w);
    if ((tid & 31) == 0) atomicAdd(cnt + d, 1.0f);
}

// fused: h1 = cnt>0 ? leaky(sum/cnt @ W0 + b0) : 0 ; p = h1 @ Weq  (2 outs/node)
// 16 nodes per block.
__global__ __launch_bounds__(256) void h1proj(const float* __restrict__ sum,
                                              const float* __restrict__ cnt,
                                              const float* __restrict__ W0,
                                              const float* __restrict__ b0,
                                              const float* __restrict__ Weq,
                                              float* __restrict__ p, int n) {
    __shared__ float Ws[128 * 64];    // 32 KB
    __shared__ float sums[16 * 128];  // 8 KB (raw sums; divide by cnt after dot)
    __shared__ float ps[32];
    int tid = threadIdx.x;
    int base = blockIdx.x * 16;
    for (int i = tid; i < 128 * 64; i += 256) Ws[i] = W0[i];
    for (int i = tid; i < 16 * 128; i += 256) {
        int r = i >> 7, c = i & 127;
        int row = base + r;
        sums[i] = row < n ? sum[(size_t)row * 128 + c] : 0.0f;
    }
    if (tid < 32) ps[tid] = 0.0f;
    __syncthreads();
    int col = tid & 63, rr = tid >> 6;
    float b0c = b0[col];
    float w0 = Weq[col * 2 + 0], w1 = Weq[col * 2 + 1];
#pragma unroll
    for (int q = 0; q < 4; q++) {
        int r = rr * 4 + q;
        int row = base + r;
        float acc = 0.0f;
#pragma unroll 8
        for (int k = 0; k < 128; k++) acc += sums[r * 128 + k] * Ws[k * 64 + col];
        float cn = row < n ? cnt[row] : 0.0f;
        if (cn > 0.0f) {
            float v = acc / cn + b0c;          // (sum@W0)/cnt + b0 == mean@W0 + b0
            float h = v > 0.0f ? v : 0.01f * v;
            atomicAdd(&ps[r * 2 + 0], h * w0);
            atomicAdd(&ps[r * 2 + 1], h * w1);
        }
    }
    __syncthreads();
    if (tid < 32) {
        int r = tid >> 1, o = tid & 1;
        int row = base + r;
        if (row < n) p[(size_t)row * 2 + o] = ps[tid];
    }
}

// layer-1 projected aggregation: acc[dst][0:2] += p[src][0:2]; cnt[dst] += 1
__global__ __launch_bounds__(256) void agg2(const float* __restrict__ p,
                                            const int* __restrict__ src,
                                            const int* __restrict__ dst,
                                            float* __restrict__ acc,
                                            float* __restrict__ cnt) {
    int e = blockIdx.x * 256 + threadIdx.x;
    if (e >= NE) return;
    int s = src[e], d = dst[e];
    const float2 v = *(const float2*)(p + (size_t)s * 2);
    atomicAdd(acc + (size_t)d * 2 + 0, v.x);
    atomicAdd(acc + (size_t)d * 2 + 1, v.y);
    atomicAdd(cnt + d, 1.0f);
}

// out = (cc>0 ? accC/cc + beqC : 0) + (cm>0 ? accM/cm + beqM : 0) + bf
__global__ __launch_bounds__(256) void final_kernel(const float* __restrict__ accC,
                                                    const float* __restrict__ cntC,
                                                    const float* __restrict__ accM,
                                                    const float* __restrict__ cntM,
                                                    const float* __restrict__ beq,
                                                    const float* __restrict__ bfv,
                                                    float* __restrict__ out) {
    int i = blockIdx.x * 256 + threadIdx.x;
    if (i >= NT) return;
    float r0 = bfv[0], r1 = bfv[1];
    float cc = cntC[i], cm = cntM[i];
    if (cc > 0.0f) {
        float inv = 1.0f / cc;
        r0 += accC[(size_t)i * 2 + 0] * inv + beq[0];
        r1 += accC[(size_t)i * 2 + 1] * inv + beq[1];
    }
    if (cm > 0.0f) {
        float inv = 1.0f / cm;
        r0 += accM[(size_t)i * 2 + 0] * inv + beq[2];
        r1 += accM[(size_t)i * 2 + 1] * inv + beq[3];
    }
    float2 o; o.x = r0; o.y = r1;
    *(float2*)(out + (size_t)i * 2) = o;
}

extern "C" void kernel_launch(void* const* d_in, const int* in_sizes, int n_in,
                              void* d_out, int out_size, void* d_ws, size_t ws_size,
                              hipStream_t stream) {
    const float* feat = (const float*)d_in[0];
    const int* src_c2t = (const int*)d_in[3];
    const int* dst_c2t = (const int*)d_in[4];
    const int* src_m2t = (const int*)d_in[5];
    const int* dst_m2t = (const int*)d_in[6];
    const int* src_t2c = (const int*)d_in[7];
    const int* dst_t2c = (const int*)d_in[8];
    const int* src_t2m = (const int*)d_in[9];
    const int* dst_t2m = (const int*)d_in[10];
    const float* W1_c2t = (const float*)d_in[13];
    const float* b1_c2t = (const float*)d_in[14];
    const float* W1_m2t = (const float*)d_in[17];
    const float* b1_m2t = (const float*)d_in[18];
    const float* W0_t2c = (const float*)d_in[19];
    const float* b0_t2c = (const float*)d_in[20];
    const float* W0_t2m = (const float*)d_in[23];
    const float* b0_t2m = (const float*)d_in[24];
    const float* Wf  = (const float*)d_in[27];
    const float* bfv = (const float*)d_in[28];

    char* ws = (char*)d_ws;
    // Phase-aliased workspace, max live footprint 52,561,040 bytes (~52.6 MB):
    // [0, 51.2M): sumBig (phase C: NC*128*4; phase M reuse: NM*128*4)
    //             then (phase 2) accC|cntCT|accM|cntMT in [0, 12M)
    float* sumBig = (float*)(ws + 0);
    float* cntC   = (float*)(ws + 51200000);   // NC*4
    float* cntM   = (float*)(ws + 10240000);   // NM*4 (phase M, after NM*128*4 sums)
    float* pC     = (float*)(ws + 51600000);   // NC*2*4 = 800,000
    float* pM     = (float*)(ws + 52400000);   // NM*2*4 = 160,000
    float* WeqC   = (float*)(ws + 52560000);   // 512 B
    float* WeqM   = (float*)(ws + 52560512);   // 512 B
    float* beq    = (float*)(ws + 52561024);   // 16 B
    float* accC   = (float*)(ws + 0);          // NT*2*4 = 4M   (phase 2)
    float* cntCT  = (float*)(ws + 4000000);    // NT*4 = 2M
    float* accM   = (float*)(ws + 6000000);    // NT*2*4 = 4M
    float* cntMT  = (float*)(ws + 10000000);   // NT*4 = 2M

    weq_kernel<<<1, 256, 0, stream>>>(W1_c2t, b1_c2t, W1_m2t, b1_m2t, Wf, WeqC, WeqM, beq);
    // layer 0, relation t2c -> clients
    hipMemsetAsync(ws, 0, 51600000, stream);   // sumBig(C) + cntC
    agg_feat<<<62500, 256, 0, stream>>>(feat, src_t2c, dst_t2c, sumBig, cntC);
    h1proj<<<6250, 256, 0, stream>>>(sumBig, cntC, W0_t2c, b0_t2c, WeqC, pC, NC);
    // layer 0, relation t2m -> merchants (reuse sum region)
    hipMemsetAsync(ws, 0, 10320000, stream);   // sumBig(M) + cntM
    agg_feat<<<62500, 256, 0, stream>>>(feat, src_t2m, dst_t2m, sumBig, cntM);
    h1proj<<<1250, 256, 0, stream>>>(sumBig, cntM, W0_t2m, b0_t2m, WeqM, pM, NM);
    // layer 1 (projected to 2 channels); sum region now dead -> alias accumulators
    hipMemsetAsync(ws, 0, 12000000, stream);   // accC|cntCT|accM|cntMT
    agg2<<<1954, 256, 0, stream>>>(pC, src_c2t, dst_c2t, accC, cntCT);
    agg2<<<1954, 256, 0, stream>>>(pM, src_m2t, dst_m2t, accM, cntMT);
    final_kernel<<<1954, 256, 0, stream>>>(accC, cntCT, accM, cntMT, beq, bfv, (float*)d_out);
}

// Round 4
// 989.193 us; speedup vs baseline: 2.4686x; 2.4686x over previous
//
#include <hip/hip_runtime.h>
#include <stdint.h>

#define NT 500000
#define NC 100000
#define NM 20000
#define NE 500000

// ---------- small dense precompute: Weq = W1 @ Wf, beq = b1 @ Wf ----------
__global__ __launch_bounds__(256) void weq_kernel(const float* __restrict__ W1c,
                                                  const float* __restrict__ b1c,
                                                  const float* __restrict__ W1m,
                                                  const float* __restrict__ b1m,
                                                  const float* __restrict__ Wf,
                                                  float* __restrict__ WeqC,
                                                  float* __restrict__ WeqM,
                                                  float* __restrict__ beq) {
    int t = threadIdx.x;
    if (t < 128) {
        int k = t >> 1, o = t & 1;
        float s = 0.0f;
        for (int j = 0; j < 64; j++) s += W1c[k * 64 + j] * Wf[j * 2 + o];
        WeqC[k * 2 + o] = s;
    } else {
        int k = (t - 128) >> 1, o = t & 1;
        float s = 0.0f;
        for (int j = 0; j < 64; j++) s += W1m[k * 64 + j] * Wf[j * 2 + o];
        WeqM[k * 2 + o] = s;
    }
    if (t < 4) {
        const float* b = (t < 2) ? b1c : b1m;
        int o = t & 1;
        float s = 0.0f;
        for (int j = 0; j < 64; j++) s += b[j] * Wf[j * 2 + o];
        beq[t] = s;
    }
}

// ---------- CSR build: hist -> 3-kernel exclusive scan -> scatter ----------
__global__ __launch_bounds__(256) void hist_kernel(const int* __restrict__ dst,
                                                   int* __restrict__ counts, int nE) {
    int e = blockIdx.x * 256 + threadIdx.x;
    if (e < nE) atomicAdd(&counts[dst[e]], 1);
}

// block b sums counts[b*1024 .. b*1024+1024)
__global__ __launch_bounds__(256) void blocksum_kernel(const int* __restrict__ counts,
                                                       int* __restrict__ blk, int n) {
    int tid = threadIdx.x;
    int base = blockIdx.x * 1024 + tid * 4;
    int s = 0;
#pragma unroll
    for (int j = 0; j < 4; j++) { int i = base + j; if (i < n) s += counts[i]; }
    for (int off = 32; off; off >>= 1) s += __shfl_down(s, off, 64);
    __shared__ int wsum[4];
    if ((tid & 63) == 0) wsum[tid >> 6] = s;
    __syncthreads();
    if (tid == 0) blk[blockIdx.x] = wsum[0] + wsum[1] + wsum[2] + wsum[3];
}

// single block: in-place exclusive scan of blk[0..nb), nb <= 256
__global__ __launch_bounds__(256) void scanblk_kernel(int* __restrict__ blk, int nb) {
    __shared__ int sh[256];
    int tid = threadIdx.x;
    int v = tid < nb ? blk[tid] : 0;
    sh[tid] = v; __syncthreads();
    for (int off = 1; off < 256; off <<= 1) {
        int t = (tid >= off) ? sh[tid - off] : 0;
        __syncthreads();
        sh[tid] += t;
        __syncthreads();
    }
    if (tid < nb) blk[tid] = sh[tid] - v;   // exclusive
}

// block b: exclusive-scan its 1024 counts in place -> rowPtr, also init cursor.
// Writes rowPtr[n] from the owner of element n-1.
__global__ __launch_bounds__(256) void scanfinal_kernel(int* __restrict__ rowPtr,
                                                        int* __restrict__ cursor,
                                                        const int* __restrict__ blkOff, int n) {
    int tid = threadIdx.x, lane = tid & 63, wv = tid >> 6;
    int base = blockIdx.x * 1024 + tid * 4;
    int c[4];
#pragma unroll
    for (int j = 0; j < 4; j++) { int i = base + j; c[j] = (i < n) ? rowPtr[i] : 0; }
    int t = c[0] + c[1] + c[2] + c[3];
    int incl = t;
    for (int off = 1; off < 64; off <<= 1) {
        int u = __shfl_up(incl, off, 64);
        if (lane >= off) incl += u;
    }
    int lexcl = incl - t;
    __shared__ int wsum[4], woff[4];
    if (lane == 63) wsum[wv] = incl;
    __syncthreads();
    if (tid == 0) { int a = 0; for (int w = 0; w < 4; w++) { woff[w] = a; a += wsum[w]; } }
    __syncthreads();
    int e = blkOff[blockIdx.x] + woff[wv] + lexcl;
#pragma unroll
    for (int j = 0; j < 4; j++) {
        int i = base + j;
        if (i < n) {
            rowPtr[i] = e;
            cursor[i] = e;
            if (i == n - 1) rowPtr[n] = e + c[j];
        }
        e += c[j];
    }
}

__global__ __launch_bounds__(256) void scatter_kernel(const int* __restrict__ src,
                                                      const int* __restrict__ dst,
                                                      int* __restrict__ cursor,
                                                      int* __restrict__ eidx, int nE) {
    int e = blockIdx.x * 256 + threadIdx.x;
    if (e >= nE) return;
    int pos = atomicAdd(&cursor[dst[e]], 1);
    eidx[pos] = src[e];
}

// ---------- gather aggregation: one wave per dst node, no atomics ----------
// half-wave (32 lanes x float4 = 512B) per edge; two edges in flight; xor-combine.
__global__ __launch_bounds__(256) void agg_csr(const float* __restrict__ feat,
                                               const int* __restrict__ rowPtr,
                                               const int* __restrict__ eidx,
                                               float* __restrict__ sum,
                                               int base, int nNodes) {
    int gw = (blockIdx.x * 256 + threadIdx.x) >> 6;
    if (gw >= nNodes) return;
    int lane = threadIdx.x & 63;
    int half = lane >> 5;            // 0 or 1: which edge of the pair
    int c4 = (lane & 31) * 4;        // channel offset
    int d = base + gw;
    int s0 = rowPtr[d], s1 = rowPtr[d + 1];
    float a0 = 0.f, a1 = 0.f, a2 = 0.f, a3 = 0.f;
    int i = s0;
    for (; i + 1 < s1; i += 2) {
        int s = eidx[i + half];
        const float4 v = *(const float4*)(feat + (size_t)s * 128 + c4);
        a0 += v.x; a1 += v.y; a2 += v.z; a3 += v.w;
    }
    if (i < s1 && half == 0) {
        int s = eidx[i];
        const float4 v = *(const float4*)(feat + (size_t)s * 128 + c4);
        a0 += v.x; a1 += v.y; a2 += v.z; a3 += v.w;
    }
    // combine the two half-wave partial sums (lane <-> lane^32, same channels)
    a0 += __shfl_xor(a0, 32, 64);
    a1 += __shfl_xor(a1, 32, 64);
    a2 += __shfl_xor(a2, 32, 64);
    a3 += __shfl_xor(a3, 32, 64);
    if (half == 0) {
        float4 o; o.x = a0; o.y = a1; o.z = a2; o.w = a3;
        *(float4*)(sum + (size_t)gw * 128 + c4) = o;
    }
}

// ---------- fused: h1 = cnt>0 ? leaky(sum/cnt @ W0 + b0) : 0 ; p = h1 @ Weq ----------
// sums are chunk-local; rowPtrB is rowPtr+chunkBase; p is p+chunkBase*2.
__global__ __launch_bounds__(256) void h1proj(const float* __restrict__ sum,
                                              const int* __restrict__ rowPtrB,
                                              const float* __restrict__ W0,
                                              const float* __restrict__ b0,
                                              const float* __restrict__ Weq,
                                              float* __restrict__ p, int n) {
    __shared__ float Ws[128 * 64];    // 32 KB
    __shared__ float sums[16 * 128];  // 8 KB
    __shared__ float ps[32];
    int tid = threadIdx.x;
    int base = blockIdx.x * 16;
    for (int i = tid; i < 128 * 64; i += 256) Ws[i] = W0[i];
    for (int i = tid; i < 16 * 128; i += 256) {
        int r = i >> 7, c = i & 127;
        int row = base + r;
        sums[i] = row < n ? sum[(size_t)row * 128 + c] : 0.0f;
    }
    if (tid < 32) ps[tid] = 0.0f;
    __syncthreads();
    int col = tid & 63, rr = tid >> 6;
    float b0c = b0[col];
    float w0 = Weq[col * 2 + 0], w1 = Weq[col * 2 + 1];
#pragma unroll
    for (int q = 0; q < 4; q++) {
        int r = rr * 4 + q;
        int row = base + r;
        float acc = 0.0f;
#pragma unroll 8
        for (int k = 0; k < 128; k++) acc += sums[r * 128 + k] * Ws[k * 64 + col];
        int cn = 0;
        if (row < n) cn = rowPtrB[row + 1] - rowPtrB[row];
        if (cn > 0) {
            float v = acc / (float)cn + b0c;
            float h = v > 0.0f ? v : 0.01f * v;
            atomicAdd(&ps[r * 2 + 0], h * w0);
            atomicAdd(&ps[r * 2 + 1], h * w1);
        }
    }
    __syncthreads();
    if (tid < 32) {
        int r = tid >> 1, o = tid & 1;
        int row = base + r;
        if (row < n) p[(size_t)row * 2 + o] = ps[tid];
    }
}

// ---------- layer-1 projected aggregation (2 ch) ----------
__global__ __launch_bounds__(256) void agg2(const float* __restrict__ p,
                                            const int* __restrict__ src,
                                            const int* __restrict__ dst,
                                            float* __restrict__ acc,
                                            float* __restrict__ cnt) {
    int e = blockIdx.x * 256 + threadIdx.x;
    if (e >= NE) return;
    int s = src[e], d = dst[e];
    const float2 v = *(const float2*)(p + (size_t)s * 2);
    atomicAdd(acc + (size_t)d * 2 + 0, v.x);
    atomicAdd(acc + (size_t)d * 2 + 1, v.y);
    atomicAdd(cnt + d, 1.0f);
}

__global__ __launch_bounds__(256) void final_kernel(const float* __restrict__ accC,
                                                    const float* __restrict__ cntC,
                                                    const float* __restrict__ accM,
                                                    const float* __restrict__ cntM,
                                                    const float* __restrict__ beq,
                                                    const float* __restrict__ bfv,
                                                    float* __restrict__ out) {
    int i = blockIdx.x * 256 + threadIdx.x;
    if (i >= NT) return;
    float r0 = bfv[0], r1 = bfv[1];
    float cc = cntC[i], cm = cntM[i];
    if (cc > 0.0f) {
        float inv = 1.0f / cc;
        r0 += accC[(size_t)i * 2 + 0] * inv + beq[0];
        r1 += accC[(size_t)i * 2 + 1] * inv + beq[1];
    }
    if (cm > 0.0f) {
        float inv = 1.0f / cm;
        r0 += accM[(size_t)i * 2 + 0] * inv + beq[2];
        r1 += accM[(size_t)i * 2 + 1] * inv + beq[3];
    }
    float2 o; o.x = r0; o.y = r1;
    *(float2*)(out + (size_t)i * 2) = o;
}

extern "C" void kernel_launch(void* const* d_in, const int* in_sizes, int n_in,
                              void* d_out, int out_size, void* d_ws, size_t ws_size,
                              hipStream_t stream) {
    const float* feat = (const float*)d_in[0];
    const int* src_c2t = (const int*)d_in[3];
    const int* dst_c2t = (const int*)d_in[4];
    const int* src_m2t = (const int*)d_in[5];
    const int* dst_m2t = (const int*)d_in[6];
    const int* src_t2c = (const int*)d_in[7];
    const int* dst_t2c = (const int*)d_in[8];
    const int* src_t2m = (const int*)d_in[9];
    const int* dst_t2m = (const int*)d_in[10];
    const float* W1_c2t = (const float*)d_in[13];
    const float* b1_c2t = (const float*)d_in[14];
    const float* W1_m2t = (const float*)d_in[17];
    const float* b1_m2t = (const float*)d_in[18];
    const float* W0_t2c = (const float*)d_in[19];
    const float* b0_t2c = (const float*)d_in[20];
    const float* W0_t2m = (const float*)d_in[23];
    const float* b0_t2m = (const float*)d_in[24];
    const float* Wf  = (const float*)d_in[27];
    const float* bfv = (const float*)d_in[28];

    char* ws = (char*)d_ws;
    // Max live footprint ~31.6 MB (well under the 52.6 MB proven safe).
    float* SUM     = (float*)(ws + 0);           // 25.6 MB: C-chunk0 / C-chunk1 / M (aliased)
    int*   rowPtrC = (int*)(ws + 25600000);      // (NC+1)*4 -> 400,016
    int*   cursorC = (int*)(ws + 26000016);      // NC*4
    int*   eidxC   = (int*)(ws + 26400016);      // NE*4 = 2,000,000
    int*   rowPtrM = (int*)(ws + 28400016);      // (NM+1)*4 -> 80,016
    int*   cursorM = (int*)(ws + 28480032);      // NM*4
    int*   eidxM   = (int*)(ws + 28560032);      // NE*4
    float* pC      = (float*)(ws + 30560032);    // NC*2*4
    float* pM      = (float*)(ws + 31360032);    // NM*2*4
    float* WeqC    = (float*)(ws + 31520032);
    float* WeqM    = (float*)(ws + 31520544);
    float* beq     = (float*)(ws + 31521056);
    int*   blkC    = (int*)(ws + 31521072);      // 98 ints
    int*   blkM    = (int*)(ws + 31521584);      // 20 ints
    // phase 2 (SUM dead):
    float* accC    = (float*)(ws + 0);           // NT*2*4 = 4 MB
    float* cntCT   = (float*)(ws + 4000000);     // NT*4 = 2 MB
    float* accM    = (float*)(ws + 6000000);     // 4 MB
    float* cntMT   = (float*)(ws + 10000000);    // 2 MB

    weq_kernel<<<1, 256, 0, stream>>>(W1_c2t, b1_c2t, W1_m2t, b1_m2t, Wf, WeqC, WeqM, beq);

    // ---- build CSR for t2c and t2m ----
    hipMemsetAsync(rowPtrC, 0, 400016, stream);
    hipMemsetAsync(rowPtrM, 0, 80016, stream);
    hist_kernel<<<1954, 256, 0, stream>>>(dst_t2c, rowPtrC, NE);
    hist_kernel<<<1954, 256, 0, stream>>>(dst_t2m, rowPtrM, NE);
    blocksum_kernel<<<98, 256, 0, stream>>>(rowPtrC, blkC, NC);
    blocksum_kernel<<<20, 256, 0, stream>>>(rowPtrM, blkM, NM);
    scanblk_kernel<<<1, 256, 0, stream>>>(blkC, 98);
    scanblk_kernel<<<1, 256, 0, stream>>>(blkM, 20);
    scanfinal_kernel<<<98, 256, 0, stream>>>(rowPtrC, cursorC, blkC, NC);
    scanfinal_kernel<<<20, 256, 0, stream>>>(rowPtrM, cursorM, blkM, NM);
    scatter_kernel<<<1954, 256, 0, stream>>>(src_t2c, dst_t2c, cursorC, eidxC, NE);
    scatter_kernel<<<1954, 256, 0, stream>>>(src_t2m, dst_t2m, cursorM, eidxM, NE);

    // ---- layer 0: gather-aggregate + fused projection, chunked ----
    // clients chunk 0: nodes [0, 50000)
    agg_csr<<<12500, 256, 0, stream>>>(feat, rowPtrC, eidxC, SUM, 0, 50000);
    h1proj<<<3125, 256, 0, stream>>>(SUM, rowPtrC, W0_t2c, b0_t2c, WeqC, pC, 50000);
    // clients chunk 1: nodes [50000, 100000)
    agg_csr<<<12500, 256, 0, stream>>>(feat, rowPtrC, eidxC, SUM, 50000, 50000);
    h1proj<<<3125, 256, 0, stream>>>(SUM, rowPtrC + 50000, W0_t2c, b0_t2c, WeqC, pC + 100000, 50000);
    // merchants: nodes [0, 20000)
    agg_csr<<<5000, 256, 0, stream>>>(feat, rowPtrM, eidxM, SUM, 0, 20000);
    h1proj<<<1250, 256, 0, stream>>>(SUM, rowPtrM, W0_t2m, b0_t2m, WeqM, pM, 20000);

    // ---- layer 1 (2-channel) ----
    hipMemsetAsync(ws, 0, 12000000, stream);
    agg2<<<1954, 256, 0, stream>>>(pC, src_c2t, dst_c2t, accC, cntCT);
    agg2<<<1954, 256, 0, stream>>>(pM, src_m2t, dst_m2t, accM, cntMT);
    final_kernel<<<1954, 256, 0, stream>>>(accC, cntCT, accM, cntMT, beq, bfv, (float*)d_out);
}